// Round 7
// baseline (393.482 us; speedup 1.0000x reference)
//
#include <hip/hip_runtime.h>
#include <hip/hip_bf16.h>

// Problem constants
#define Bq 4
#define Nq 2048
#define Mq 2048
#define Dq 1024
#define Hq 16
// HD = 64; logits in exp2 domain: scale 0.125*log2e folded into Q GEMM,
// log2e folded into bias prepass. Defer-max online softmax (R3/R5-proven;
// no-max variant FAILS numerically — verified twice, R4/R6, absmax 1.9e-2).

typedef __attribute__((ext_vector_type(8))) short short8;
typedef __attribute__((ext_vector_type(4))) short short4v;
typedef __attribute__((ext_vector_type(4))) float floatx4;
typedef __attribute__((ext_vector_type(16))) float floatx16;
typedef __attribute__((ext_vector_type(4))) unsigned uint4v;

static __device__ __forceinline__ short f2bf(float f) {
    __hip_bfloat16 h = __float2bfloat16(f);   // RNE
    short r;
    __builtin_memcpy(&r, &h, 2);
    return r;
}
static __device__ __forceinline__ float bf2f(short s) {
    unsigned u = ((unsigned)(unsigned short)s) << 16;
    float f;
    __builtin_memcpy(&f, &u, 4);
    return f;
}
static __device__ __forceinline__ unsigned cvtpk_bf16(float lo, float hi) {
    unsigned r;
    asm("v_cvt_pk_bf16_f32 %0, %1, %2" : "=v"(r) : "v"(lo), "v"(hi));
    return r;
}
static __device__ __forceinline__ void swap32(unsigned &a, unsigned &b) {
    asm("v_permlane32_swap_b32 %0, %1" : "+v"(a), "+v"(b));
}
static __device__ __forceinline__ float exp2_fast(float x) {
    float r;
    asm("v_exp_f32 %0, %1" : "=v"(r) : "v"(x));   // D = 2^S0
    return r;
}
static __device__ __forceinline__ void gld16(const void* g, void* l) {
    __builtin_amdgcn_global_load_lds(
        (const __attribute__((address_space(1))) unsigned int*)g,
        (__attribute__((address_space(3))) unsigned int*)l, 16, 0, 0);
}

// ---------------------------------------------------------------------------
// bias prepass: bm[b][n][m] = bf16(mask ? -1e38 : bias*log2e)
// ---------------------------------------------------------------------------
__global__ void bias_prep(const float* __restrict__ bias, const int* __restrict__ mask,
                          short* __restrict__ out)
{
    const long i = ((long)blockIdx.x * 256 + threadIdx.x) * 8;
    const int m = (int)(i & (Mq - 1));
    const int b = (int)(i >> 22);           // i / (2048*2048)
    floatx4 f0 = *(const floatx4*)(bias + i);
    floatx4 f1 = *(const floatx4*)(bias + i + 4);
    const int* mp = mask + b * Mq + m;
    short8 o;
#pragma unroll
    for (int e = 0; e < 4; ++e) {
        o[e]     = mp[e]     ? f2bf(-1e38f) : f2bf(f0[e] * 1.44269504f);
        o[e + 4] = mp[e + 4] ? f2bf(-1e38f) : f2bf(f1[e] * 1.44269504f);
    }
    *(short8*)(out + i) = o;
}

// ---------------------------------------------------------------------------
// f32 -> bf16 bulk convert via RNE f2bf
// ---------------------------------------------------------------------------
__global__ void cvt_bf(const float* __restrict__ s0, const float* __restrict__ s1,
                       const float* __restrict__ s2, const float* __restrict__ s3,
                       short* __restrict__ out, long per)
{
    const int z = blockIdx.y;
    const float* s = (z == 0) ? s0 : (z == 1) ? s1 : (z == 2) ? s2 : s3;
    short* d = out + (long)z * per;
    const long i = ((long)blockIdx.x * 256 + threadIdx.x) * 8;
    floatx4 f0 = *(const floatx4*)(s + i);
    floatx4 f1 = *(const floatx4*)(s + i + 4);
    short8 o;
#pragma unroll
    for (int e = 0; e < 4; ++e) { o[e] = f2bf(f0[e]); o[e + 4] = f2bf(f1[e]); }
    *(short8*)(d + i) = o;
}

// ---------------------------------------------------------------------------
// Batched GEMM (all-bf16): C[r][c] = (sum_k A[r][k]*W[c][k] + bias[c])*scale
// 128x128 tile, 4 waves, BK=32, LDS dbuf, both operands via global_load_lds
// w=16 with pre-swizzled source. omode: 0 bf16, 1 bf16 batch-transposed, 2 f32.
// ---------------------------------------------------------------------------
struct GB {
    const short* A[3];
    const short* W[3];
    const float* bias[3];
    void* C[3];
    float scale[3];
    int omode[3];
};

__global__ __launch_bounds__(256, 3)
void gemm_all(GB gb, int K)
{
    __shared__ __align__(16) short As[2][128 * 32];
    __shared__ __align__(16) short Bs[2][128 * 32];

    const int z = blockIdx.z;
    const short* Ap = gb.A[z];
    const short* Wp = gb.W[z];

    const int tid = threadIdx.x;
    const int lane = tid & 63;
    const int wid = tid >> 6;
    const int wr = wid >> 1, wc = wid & 1;
    const int g = lane >> 4, c = lane & 15;
    const long row0 = (long)blockIdx.x * 128;
    const int col0 = blockIdx.y * 128;

    const int R0 = tid >> 2;
    const int ub = (tid & 3) ^ ((R0 >> 1) & 3);
    const short* asrc = Ap + (row0 + R0) * (long)K + ub * 8;
    const short* bsrc = Wp + ((long)col0 + R0) * K + ub * 8;

    floatx4 acc[4][4];
#pragma unroll
    for (int i = 0; i < 4; ++i)
#pragma unroll
        for (int j = 0; j < 4; ++j) acc[i][j] = (floatx4)0.0f;

#define GSTAGE(buf, koff) do {                                                \
        char* ad = (char*)As + (buf) * 8192 + wid * 1024;                     \
        char* bd = (char*)Bs + (buf) * 8192 + wid * 1024;                     \
        gld16(asrc + (koff), ad);                                             \
        gld16(asrc + 64L * K + (koff), ad + 4096);                            \
        gld16(bsrc + (koff), bd);                                             \
        gld16(bsrc + 64L * K + (koff), bd + 4096);                            \
    } while (0)

    GSTAGE(0, 0);
    __syncthreads();

    int buf = 0;
    for (int kt = 0; kt < K; kt += 32) {
        if (kt + 32 < K) GSTAGE(buf ^ 1, kt + 32);
        short8* As8 = (short8*)((char*)As + buf * 8192);
        short8* Bs8 = (short8*)((char*)Bs + buf * 8192);
        short8 af[4], bfq[4];
#pragma unroll
        for (int fm = 0; fm < 4; ++fm) {
            const int r = wr * 64 + fm * 16 + c;
            af[fm] = As8[r * 4 + (g ^ ((r >> 1) & 3))];
        }
#pragma unroll
        for (int fn = 0; fn < 4; ++fn) {
            const int cc = wc * 64 + fn * 16 + c;
            bfq[fn] = Bs8[cc * 4 + (g ^ ((cc >> 1) & 3))];
        }
#pragma unroll
        for (int fm = 0; fm < 4; ++fm)
#pragma unroll
            for (int fn = 0; fn < 4; ++fn)
                acc[fm][fn] = __builtin_amdgcn_mfma_f32_16x16x32_bf16(af[fm], bfq[fn], acc[fm][fn], 0, 0, 0);
        __syncthreads();
        buf ^= 1;
    }
#undef GSTAGE

    const float sc = gb.scale[z];
    const float* bp = gb.bias[z];
    const int om = gb.omode[z];
    void* Cp = gb.C[z];
#pragma unroll
    for (int fn = 0; fn < 4; ++fn) {
        const int ccol = col0 + wc * 64 + fn * 16 + c;
        const float bv = bp[ccol];
#pragma unroll
        for (int fm = 0; fm < 4; ++fm) {
            const long r0 = row0 + wr * 64 + fm * 16 + g * 4;
#pragma unroll
            for (int reg = 0; reg < 4; ++reg) {
                const float val = (acc[fm][fn][reg] + bv) * sc;
                const long rr = r0 + reg;
                if (om == 0) {
                    ((short*)Cp)[rr * Dq + ccol] = f2bf(val);
                } else if (om == 1) {
                    const long idx = ((long)(rr >> 11) * Dq + ccol) * (long)Mq + (rr & (Mq - 1));
                    ((short*)Cp)[idx] = f2bf(val);
                } else {
                    ((float*)Cp)[rr * Dq + ccol] = val;
                }
            }
        }
    }
}

// ---------------------------------------------------------------------------
// Fused flash attention: swapped-operand 32x32, exp2 domain, DEFER-MAX
// (R3/R5-proven), bias prefetched across the barrier (dbuf bb regs),
// setprio around MFMA, 2x-unrolled even/odd tile loop.
// Grid 1024 = (qt 0..15)*(bh 0..63); block 256 = 4 waves, wave = 32 q-rows.
// ---------------------------------------------------------------------------
__global__ __launch_bounds__(256, 4)
void attn_fused(const short* __restrict__ qg_, const short* __restrict__ kg_,
                const short* __restrict__ vtg, const short* __restrict__ bmg,
                short* __restrict__ outg)
{
    __shared__ __align__(16) short k_lds[2][64 * 64];   // 2 x 8KB
    __shared__ __align__(16) short v_lds[2][64 * 64];   // 2 x 8KB

    const int tid = threadIdx.x;
    const int lane = tid & 63;
    const int w = tid >> 6;          // 0..3
    const int hi = lane >> 5;
    const int q31 = lane & 31;

    const int blk = blockIdx.x;
    const int bh = blk & 63;
    const int qt = blk >> 6;
    const int b = bh >> 4, h = bh & 15;

    const long qbase = (long)b * Nq + qt * 128 + w * 32;   // + q31

    short8 qf[4];
#pragma unroll
    for (int ks = 0; ks < 4; ++ks)
        qf[ks] = *(const short8*)(qg_ + (qbase + q31) * Dq + h * 64 + ks * 16 + hi * 8);

    floatx16 oa0 = (floatx16)0.0f, oa1 = (floatx16)0.0f;
    float m_s = -1e37f, l_s = 0.0f;

    const int sr = tid >> 3;                       // 0..31
    const int su = (tid & 7) ^ (sr & 7);
    const char* ksrc = (const char*)(kg_ + ((long)b * Mq + sr) * Dq + h * 64 + su * 8);
    const char* vsrc = (const char*)(vtg + ((long)b * Dq + h * 64 + sr) * Mq + su * 8);
    const short* bbase = bmg + (qbase + q31) * Mq + hi * 4;

#define STAGE(bf, kt2) do {                                                   \
        const long j0b = (long)(kt2) * 64;                                    \
        char* kd = (char*)k_lds + (bf) * 8192 + w * 1024;                     \
        char* vd = (char*)v_lds + (bf) * 8192 + w * 1024;                     \
        gld16(ksrc + j0b * (Dq * 2), kd);                                     \
        gld16(ksrc + (j0b + 32) * (Dq * 2), kd + 4096);                       \
        gld16(vsrc + j0b * 2, vd);                                            \
        gld16(vsrc + 32L * Mq * 2 + j0b * 2, vd + 4096);                      \
    } while (0)

#define LOADBB(bb, kt2) do {                                                  \
        const short* brow_ = bbase + (long)(kt2) * 64;                        \
        _Pragma("unroll")                                                     \
        for (int kg = 0; kg < 2; ++kg)                                        \
            _Pragma("unroll")                                                 \
            for (int Qh = 0; Qh < 4; ++Qh)                                    \
                bb[kg * 4 + Qh] = *(const short4v*)(brow_ + kg * 32 + Qh * 8);\
    } while (0)

#define COMPUTE(kb, vb, bb) do {                                              \
        floatx16 sa0, sa1;                                                    \
        _Pragma("unroll")                                                     \
        for (int Qh = 0; Qh < 4; ++Qh)                                        \
            _Pragma("unroll")                                                 \
            for (int e = 0; e < 4; ++e) {                                     \
                sa0[Qh * 4 + e] = bf2f(bb[Qh][e]);                            \
                sa1[Qh * 4 + e] = bf2f(bb[4 + Qh][e]);                        \
            }                                                                 \
        {                                                                     \
            short8 kf[4];                                                     \
            _Pragma("unroll")                                                 \
            for (int ks = 0; ks < 4; ++ks)                                    \
                kf[ks] = *(const short8*)((kb) + q31 * 128 + (((2 * ks + hi) ^ (q31 & 7)) * 16)); \
            __builtin_amdgcn_s_setprio(1);                                    \
            _Pragma("unroll")                                                 \
            for (int ks = 0; ks < 4; ++ks)                                    \
                sa0 = __builtin_amdgcn_mfma_f32_32x32x16_bf16(kf[ks], qf[ks], sa0, 0, 0, 0); \
            __builtin_amdgcn_s_setprio(0);                                    \
        }                                                                     \
        {                                                                     \
            short8 kf[4];                                                     \
            const int r1 = 32 + q31;                                          \
            _Pragma("unroll")                                                 \
            for (int ks = 0; ks < 4; ++ks)                                    \
                kf[ks] = *(const short8*)((kb) + r1 * 128 + (((2 * ks + hi) ^ (r1 & 7)) * 16)); \
            __builtin_amdgcn_s_setprio(1);                                    \
            _Pragma("unroll")                                                 \
            for (int ks = 0; ks < 4; ++ks)                                    \
                sa1 = __builtin_amdgcn_mfma_f32_32x32x16_bf16(kf[ks], qf[ks], sa1, 0, 0, 0); \
            __builtin_amdgcn_s_setprio(0);                                    \
        }                                                                     \
        /* defer-max online softmax (R3/R5-proven) */                         \
        {                                                                     \
            float a0 = fmaxf(fmaxf(sa0[0], sa0[1]), fmaxf(sa0[2], sa0[3]));   \
            float a1 = fmaxf(fmaxf(sa0[4], sa0[5]), fmaxf(sa0[6], sa0[7]));   \
            float a2 = fmaxf(fmaxf(sa0[8], sa0[9]), fmaxf(sa0[10], sa0[11])); \
            float a3 = fmaxf(fmaxf(sa0[12], sa0[13]), fmaxf(sa0[14], sa0[15]));\
            float a4 = fmaxf(fmaxf(sa1[0], sa1[1]), fmaxf(sa1[2], sa1[3]));   \
            float a5 = fmaxf(fmaxf(sa1[4], sa1[5]), fmaxf(sa1[6], sa1[7]));   \
            float a6 = fmaxf(fmaxf(sa1[8], sa1[9]), fmaxf(sa1[10], sa1[11])); \
            float a7 = fmaxf(fmaxf(sa1[12], sa1[13]), fmaxf(sa1[14], sa1[15]));\
            float pm = fmaxf(fmaxf(fmaxf(a0, a1), fmaxf(a2, a3)),             \
                             fmaxf(fmaxf(a4, a5), fmaxf(a6, a7)));            \
            pm = fmaxf(pm, __shfl_xor(pm, 32));                               \
            if (!__all(pm <= m_s + 11.5f)) {                                  \
                const float mn = fmaxf(m_s, pm);                              \
                const float al = exp2_fast(m_s - mn);                         \
                l_s *= al;                                                    \
                oa0 *= al; oa1 *= al;                                         \
                m_s = mn;                                                     \
            }                                                                 \
        }                                                                     \
        _Pragma("unroll")                                                     \
        for (int j = 0; j < 16; ++j) {                                        \
            sa0[j] = exp2_fast(sa0[j] - m_s);                                 \
            sa1[j] = exp2_fast(sa1[j] - m_s);                                 \
        }                                                                     \
        {                                                                     \
            const float t0 = (sa0[0] + sa0[1]) + (sa0[2] + sa0[3]);           \
            const float t1 = (sa0[4] + sa0[5]) + (sa0[6] + sa0[7]);           \
            const float t2 = (sa0[8] + sa0[9]) + (sa0[10] + sa0[11]);         \
            const float t3 = (sa0[12] + sa0[13]) + (sa0[14] + sa0[15]);       \
            const float t4 = (sa1[0] + sa1[1]) + (sa1[2] + sa1[3]);           \
            const float t5 = (sa1[4] + sa1[5]) + (sa1[6] + sa1[7]);           \
            const float t6 = (sa1[8] + sa1[9]) + (sa1[10] + sa1[11]);         \
            const float t7 = (sa1[12] + sa1[13]) + (sa1[14] + sa1[15]);       \
            float rs = ((t0 + t1) + (t2 + t3)) + ((t4 + t5) + (t6 + t7));     \
            rs += __shfl_xor(rs, 32);                                         \
            l_s += rs;                                                        \
        }                                                                     \
        uint4v pw0, pw1, pw2, pw3;                                            \
        {                                                                     \
            unsigned w0 = cvtpk_bf16(sa0[0], sa0[1]);                         \
            unsigned w1 = cvtpk_bf16(sa0[2], sa0[3]);                         \
            unsigned w2 = cvtpk_bf16(sa0[4], sa0[5]);                         \
            unsigned w3 = cvtpk_bf16(sa0[6], sa0[7]);                         \
            swap32(w0, w2); swap32(w1, w3);                                   \
            pw0[0] = w0; pw0[1] = w1; pw0[2] = w2; pw0[3] = w3;               \
            unsigned w4 = cvtpk_bf16(sa0[8], sa0[9]);                         \
            unsigned w5 = cvtpk_bf16(sa0[10], sa0[11]);                       \
            unsigned w6 = cvtpk_bf16(sa0[12], sa0[13]);                       \
            unsigned w7 = cvtpk_bf16(sa0[14], sa0[15]);                       \
            swap32(w4, w6); swap32(w5, w7);                                   \
            pw1[0] = w4; pw1[1] = w5; pw1[2] = w6; pw1[3] = w7;               \
            unsigned x0 = cvtpk_bf16(sa1[0], sa1[1]);                         \
            unsigned x1 = cvtpk_bf16(sa1[2], sa1[3]);                         \
            unsigned x2 = cvtpk_bf16(sa1[4], sa1[5]);                         \
            unsigned x3 = cvtpk_bf16(sa1[6], sa1[7]);                         \
            swap32(x0, x2); swap32(x1, x3);                                   \
            pw2[0] = x0; pw2[1] = x1; pw2[2] = x2; pw2[3] = x3;               \
            unsigned x4 = cvtpk_bf16(sa1[8], sa1[9]);                         \
            unsigned x5 = cvtpk_bf16(sa1[10], sa1[11]);                       \
            unsigned x6 = cvtpk_bf16(sa1[12], sa1[13]);                       \
            unsigned x7 = cvtpk_bf16(sa1[14], sa1[15]);                       \
            swap32(x4, x6); swap32(x5, x7);                                   \
            pw3[0] = x4; pw3[1] = x5; pw3[2] = x6; pw3[3] = x7;               \
        }                                                                     \
        {                                                                     \
            short8 vf[4];                                                     \
            _Pragma("unroll")                                                 \
            for (int ks = 0; ks < 4; ++ks)                                    \
                vf[ks] = *(const short8*)((vb) + q31 * 128 + (((2 * ks + hi) ^ (q31 & 7)) * 16)); \
            __builtin_amdgcn_s_setprio(1);                                    \
            oa0 = __builtin_amdgcn_mfma_f32_32x32x16_bf16(vf[0], __builtin_bit_cast(short8, pw0), oa0, 0, 0, 0); \
            oa0 = __builtin_amdgcn_mfma_f32_32x32x16_bf16(vf[1], __builtin_bit_cast(short8, pw1), oa0, 0, 0, 0); \
            oa0 = __builtin_amdgcn_mfma_f32_32x32x16_bf16(vf[2], __builtin_bit_cast(short8, pw2), oa0, 0, 0, 0); \
            oa0 = __builtin_amdgcn_mfma_f32_32x32x16_bf16(vf[3], __builtin_bit_cast(short8, pw3), oa0, 0, 0, 0); \
            __builtin_amdgcn_s_setprio(0);                                    \
        }                                                                     \
        {                                                                     \
            short8 vf[4];                                                     \
            const int r1 = 32 + q31;                                          \
            _Pragma("unroll")                                                 \
            for (int ks = 0; ks < 4; ++ks)                                    \
                vf[ks] = *(const short8*)((vb) + r1 * 128 + (((2 * ks + hi) ^ (r1 & 7)) * 16)); \
            __builtin_amdgcn_s_setprio(1);                                    \
            oa1 = __builtin_amdgcn_mfma_f32_32x32x16_bf16(vf[0], __builtin_bit_cast(short8, pw0), oa1, 0, 0, 0); \
            oa1 = __builtin_amdgcn_mfma_f32_32x32x16_bf16(vf[1], __builtin_bit_cast(short8, pw1), oa1, 0, 0, 0); \
            oa1 = __builtin_amdgcn_mfma_f32_32x32x16_bf16(vf[2], __builtin_bit_cast(short8, pw2), oa1, 0, 0, 0); \
            oa1 = __builtin_amdgcn_mfma_f32_32x32x16_bf16(vf[3], __builtin_bit_cast(short8, pw3), oa1, 0, 0, 0); \
            __builtin_amdgcn_s_setprio(0);                                    \
        }                                                                     \
    } while (0)

    short4v bbA[8], bbB[8];
    const char* kb0 = (const char*)k_lds;
    const char* kb1 = (const char*)k_lds + 8192;
    const char* vb0 = (const char*)v_lds;
    const char* vb1 = (const char*)v_lds + 8192;

    STAGE(0, 0);
    LOADBB(bbA, 0);
    __syncthreads();

    for (int it = 0; it < 16; ++it) {
        const int t0 = 2 * it;
        // even: compute buf0 = tile t0; prefetch tile t0+1 (always valid)
        STAGE(1, t0 + 1);
        LOADBB(bbB, t0 + 1);
        COMPUTE(kb0, vb0, bbA);
        __syncthreads();
        // odd: compute buf1 = tile t0+1; prefetch tile t0+2 if it exists
        if (it < 15) {
            STAGE(0, t0 + 2);
            LOADBB(bbA, t0 + 2);
        }
        COMPUTE(kb1, vb1, bbB);
        __syncthreads();
    }
#undef STAGE
#undef LOADBB
#undef COMPUTE

    const float invl = 1.0f / l_s;
    short* op = outg + (qbase + q31) * Dq + h * 64;
#pragma unroll
    for (int Qh = 0; Qh < 4; ++Qh) {
        short4v t0v, t1v;
#pragma unroll
        for (int e = 0; e < 4; ++e) {
            t0v[e] = f2bf(oa0[Qh * 4 + e] * invl);
            t1v[e] = f2bf(oa1[Qh * 4 + e] * invl);
        }
        *(short4v*)(op + Qh * 8 + hi * 4) = t0v;
        *(short4v*)(op + 32 + Qh * 8 + hi * 4) = t1v;
    }
}

// ---------------------------------------------------------------------------
extern "C" void kernel_launch(void* const* d_in, const int* in_sizes, int n_in,
                              void* d_out, int out_size, void* d_ws, size_t ws_size,
                              hipStream_t stream)
{
    const float* Q    = (const float*)d_in[0];
    const float* K    = (const float*)d_in[1];
    const float* V    = (const float*)d_in[2];
    const float* bias = (const float*)d_in[3];
    const int*   mask = (const int*)d_in[4];
    const float* Wq   = (const float*)d_in[5];
    const float* bq   = (const float*)d_in[6];
    const float* Wk   = (const float*)d_in[7];
    const float* bk   = (const float*)d_in[8];
    const float* Wv   = (const float*)d_in[9];
    const float* bv   = (const float*)d_in[10];
    const float* Wo   = (const float*)d_in[11];
    const float* bo   = (const float*)d_in[12];

    // ws layout (shorts), 109 MB total (R3/R5-proven footprint):
    //   q | k | vT | a(=qin first) | bm(=kin/vin first, 2TSZ) | W (4x1.05M)
    const size_t TSZ = (size_t)Bq * Nq * Dq;       // 8,388,608
    short* q_ws  = (short*)d_ws;
    short* k_ws  = q_ws  + TSZ;
    short* vt_ws = k_ws  + TSZ;
    short* a_ws  = vt_ws + TSZ;
    short* bm_ws = a_ws  + TSZ;
    short* w_ws  = bm_ws + 2 * TSZ;
    short* qin_ws = a_ws;
    short* kin_ws = bm_ws;
    short* vin_ws = bm_ws + TSZ;
    (void)ws_size;

    cvt_bf<<<dim3(512, 4), dim3(256), 0, stream>>>(Wq, Wk, Wv, Wo, w_ws, (long)Dq * Dq);
    cvt_bf<<<dim3(4096, 3), dim3(256), 0, stream>>>(Q, K, V, V, qin_ws, (long)TSZ);

    GB g1{};
    g1.A[0] = qin_ws; g1.A[1] = kin_ws; g1.A[2] = vin_ws;
    g1.W[0] = w_ws; g1.W[1] = w_ws + Dq * Dq; g1.W[2] = w_ws + 2 * Dq * Dq;
    g1.bias[0] = bq; g1.bias[1] = bk; g1.bias[2] = bv;
    g1.C[0] = q_ws; g1.C[1] = k_ws; g1.C[2] = vt_ws;
    g1.scale[0] = 0.125f * 1.44269504f; g1.scale[1] = 1.0f; g1.scale[2] = 1.0f;
    g1.omode[0] = 0; g1.omode[1] = 0; g1.omode[2] = 1;
    gemm_all<<<dim3(64, 8, 3), dim3(256), 0, stream>>>(g1, Dq);

    bias_prep<<<dim3(8192), dim3(256), 0, stream>>>(bias, mask, bm_ws);

    attn_fused<<<dim3(1024), dim3(256), 0, stream>>>(q_ws, k_ws, vt_ws, bm_ws, a_ws);

    GB g2{};
    g2.A[0] = a_ws;
    g2.W[0] = w_ws + 3 * Dq * Dq;
    g2.bias[0] = bo;
    g2.C[0] = d_out;
    g2.scale[0] = 1.0f;
    g2.omode[0] = 2;
    gemm_all<<<dim3(64, 8, 1), dim3(256), 0, stream>>>(g2, Dq);
}

// Round 9
// 330.024 us; speedup vs baseline: 1.1923x; 1.1923x over previous
//
#include <hip/hip_runtime.h>
#include <hip/hip_bf16.h>

// Problem constants
#define Bq 4
#define Nq 2048
#define Mq 2048
#define Dq 1024
#define Hq 16
// HD = 64; logits in exp2 domain: scale 0.125*log2e folded into Q GEMM,
// log2e folded into bias prepass. Defer-max online softmax (R3/R5-proven;
// no-max FAILS: R4/R6 absmax 1.9e-2). NO setprio in attn (R7: FETCH 2x).
// Cross-half reduce MUST be __shfl_xor(x,32): permlane32_swap(a,b) with a==b
// coalesces to one register and half-swaps instead of reducing (R8, 7.9e-2).

typedef __attribute__((ext_vector_type(8))) short short8;
typedef __attribute__((ext_vector_type(4))) short short4v;
typedef __attribute__((ext_vector_type(4))) float floatx4;
typedef __attribute__((ext_vector_type(16))) float floatx16;
typedef __attribute__((ext_vector_type(4))) unsigned uint4v;

static __device__ __forceinline__ short f2bf(float f) {
    __hip_bfloat16 h = __float2bfloat16(f);   // RNE
    short r;
    __builtin_memcpy(&r, &h, 2);
    return r;
}
static __device__ __forceinline__ float bf2f(short s) {
    unsigned u = ((unsigned)(unsigned short)s) << 16;
    float f;
    __builtin_memcpy(&f, &u, 4);
    return f;
}
static __device__ __forceinline__ unsigned cvtpk_bf16(float lo, float hi) {
    unsigned r;
    asm("v_cvt_pk_bf16_f32 %0, %1, %2" : "=v"(r) : "v"(lo), "v"(hi));
    return r;
}
static __device__ __forceinline__ void swap32(unsigned &a, unsigned &b) {
    asm("v_permlane32_swap_b32 %0, %1" : "+v"(a), "+v"(b));
}
static __device__ __forceinline__ float exp2_fast(float x) {
    float r;
    asm("v_exp_f32 %0, %1" : "=v"(r) : "v"(x));   // D = 2^S0
    return r;
}
static __device__ __forceinline__ void gld16(const void* g, void* l) {
    __builtin_amdgcn_global_load_lds(
        (const __attribute__((address_space(1))) unsigned int*)g,
        (__attribute__((address_space(3))) unsigned int*)l, 16, 0, 0);
}

// ---------------------------------------------------------------------------
// bias prepass: bm[b][n][m] = bf16(mask ? -1e38 : bias*log2e)
// ---------------------------------------------------------------------------
__global__ void bias_prep(const float* __restrict__ bias, const int* __restrict__ mask,
                          short* __restrict__ out)
{
    const long i = ((long)blockIdx.x * 256 + threadIdx.x) * 8;
    const int m = (int)(i & (Mq - 1));
    const int b = (int)(i >> 22);           // i / (2048*2048)
    floatx4 f0 = *(const floatx4*)(bias + i);
    floatx4 f1 = *(const floatx4*)(bias + i + 4);
    const int* mp = mask + b * Mq + m;
    short8 o;
#pragma unroll
    for (int e = 0; e < 4; ++e) {
        o[e]     = mp[e]     ? f2bf(-1e38f) : f2bf(f0[e] * 1.44269504f);
        o[e + 4] = mp[e + 4] ? f2bf(-1e38f) : f2bf(f1[e] * 1.44269504f);
    }
    *(short8*)(out + i) = o;
}

// ---------------------------------------------------------------------------
// f32 -> bf16 bulk convert via RNE f2bf
// ---------------------------------------------------------------------------
__global__ void cvt_bf(const float* __restrict__ s0, const float* __restrict__ s1,
                       const float* __restrict__ s2, const float* __restrict__ s3,
                       short* __restrict__ out, long per)
{
    const int z = blockIdx.y;
    const float* s = (z == 0) ? s0 : (z == 1) ? s1 : (z == 2) ? s2 : s3;
    short* d = out + (long)z * per;
    const long i = ((long)blockIdx.x * 256 + threadIdx.x) * 8;
    floatx4 f0 = *(const floatx4*)(s + i);
    floatx4 f1 = *(const floatx4*)(s + i + 4);
    short8 o;
#pragma unroll
    for (int e = 0; e < 4; ++e) { o[e] = f2bf(f0[e]); o[e + 4] = f2bf(f1[e]); }
    *(short8*)(d + i) = o;
}

// ---------------------------------------------------------------------------
// Batched GEMM (all-bf16): C[r][c] = (sum_k A[r][k]*W[c][k] + bias[c])*scale
// 128x128 tile, 4 waves, BK=32, LDS dbuf, both operands via global_load_lds
// w=16 with pre-swizzled source. omode: 0 bf16, 1 bf16 batch-transposed, 2 f32.
// ---------------------------------------------------------------------------
struct GB {
    const short* A[3];
    const short* W[3];
    const float* bias[3];
    void* C[3];
    float scale[3];
    int omode[3];
};

__global__ __launch_bounds__(256, 3)
void gemm_all(GB gb, int K)
{
    __shared__ __align__(16) short As[2][128 * 32];
    __shared__ __align__(16) short Bs[2][128 * 32];

    const int z = blockIdx.z;
    const short* Ap = gb.A[z];
    const short* Wp = gb.W[z];

    const int tid = threadIdx.x;
    const int lane = tid & 63;
    const int wid = tid >> 6;
    const int wr = wid >> 1, wc = wid & 1;
    const int g = lane >> 4, c = lane & 15;
    const long row0 = (long)blockIdx.x * 128;
    const int col0 = blockIdx.y * 128;

    const int R0 = tid >> 2;
    const int ub = (tid & 3) ^ ((R0 >> 1) & 3);
    const short* asrc = Ap + (row0 + R0) * (long)K + ub * 8;
    const short* bsrc = Wp + ((long)col0 + R0) * K + ub * 8;

    floatx4 acc[4][4];
#pragma unroll
    for (int i = 0; i < 4; ++i)
#pragma unroll
        for (int j = 0; j < 4; ++j) acc[i][j] = (floatx4)0.0f;

#define GSTAGE(buf, koff) do {                                                \
        char* ad = (char*)As + (buf) * 8192 + wid * 1024;                     \
        char* bd = (char*)Bs + (buf) * 8192 + wid * 1024;                     \
        gld16(asrc + (koff), ad);                                             \
        gld16(asrc + 64L * K + (koff), ad + 4096);                            \
        gld16(bsrc + (koff), bd);                                             \
        gld16(bsrc + 64L * K + (koff), bd + 4096);                            \
    } while (0)

    GSTAGE(0, 0);
    __syncthreads();

    int buf = 0;
    for (int kt = 0; kt < K; kt += 32) {
        if (kt + 32 < K) GSTAGE(buf ^ 1, kt + 32);
        short8* As8 = (short8*)((char*)As + buf * 8192);
        short8* Bs8 = (short8*)((char*)Bs + buf * 8192);
        short8 af[4], bfq[4];
#pragma unroll
        for (int fm = 0; fm < 4; ++fm) {
            const int r = wr * 64 + fm * 16 + c;
            af[fm] = As8[r * 4 + (g ^ ((r >> 1) & 3))];
        }
#pragma unroll
        for (int fn = 0; fn < 4; ++fn) {
            const int cc = wc * 64 + fn * 16 + c;
            bfq[fn] = Bs8[cc * 4 + (g ^ ((cc >> 1) & 3))];
        }
#pragma unroll
        for (int fm = 0; fm < 4; ++fm)
#pragma unroll
            for (int fn = 0; fn < 4; ++fn)
                acc[fm][fn] = __builtin_amdgcn_mfma_f32_16x16x32_bf16(af[fm], bfq[fn], acc[fm][fn], 0, 0, 0);
        __syncthreads();
        buf ^= 1;
    }
#undef GSTAGE

    const float sc = gb.scale[z];
    const float* bp = gb.bias[z];
    const int om = gb.omode[z];
    void* Cp = gb.C[z];
#pragma unroll
    for (int fn = 0; fn < 4; ++fn) {
        const int ccol = col0 + wc * 64 + fn * 16 + c;
        const float bv = bp[ccol];
#pragma unroll
        for (int fm = 0; fm < 4; ++fm) {
            const long r0 = row0 + wr * 64 + fm * 16 + g * 4;
#pragma unroll
            for (int reg = 0; reg < 4; ++reg) {
                const float val = (acc[fm][fn][reg] + bv) * sc;
                const long rr = r0 + reg;
                if (om == 0) {
                    ((short*)Cp)[rr * Dq + ccol] = f2bf(val);
                } else if (om == 1) {
                    const long idx = ((long)(rr >> 11) * Dq + ccol) * (long)Mq + (rr & (Mq - 1));
                    ((short*)Cp)[idx] = f2bf(val);
                } else {
                    ((float*)Cp)[rr * Dq + ccol] = val;
                }
            }
        }
    }
}

// ---------------------------------------------------------------------------
// Fused flash attention: swapped-operand 32x32, exp2 domain, defer-max.
// R5 schedule (single loop, one barrier/tile, NO setprio) + bias register
// prefetch (bbA/bbB rotate). Cross-half reduces via __shfl_xor (R8 lesson).
// Grid 1024 = (qt 0..15)*(bh 0..63); block 256 = 4 waves, wave = 32 q-rows.
// ---------------------------------------------------------------------------
__global__ __launch_bounds__(256, 4)
void attn_fused(const short* __restrict__ qg_, const short* __restrict__ kg_,
                const short* __restrict__ vtg, const short* __restrict__ bmg,
                short* __restrict__ outg)
{
    __shared__ __align__(16) short k_lds[2][64 * 64];   // 2 x 8KB
    __shared__ __align__(16) short v_lds[2][64 * 64];   // 2 x 8KB

    const int tid = threadIdx.x;
    const int lane = tid & 63;
    const int w = tid >> 6;          // 0..3
    const int hi = lane >> 5;
    const int q31 = lane & 31;

    // bh = blk&63 -> blk%8 = bh%8: all 16 qt-blocks of one (b,h) on one XCD.
    const int blk = blockIdx.x;
    const int bh = blk & 63;
    const int qt = blk >> 6;
    const int b = bh >> 4, h = bh & 15;

    const long qbase = (long)b * Nq + qt * 128 + w * 32;   // + q31

    short8 qf[4];
#pragma unroll
    for (int ks = 0; ks < 4; ++ks)
        qf[ks] = *(const short8*)(qg_ + (qbase + q31) * Dq + h * 64 + ks * 16 + hi * 8);

    floatx16 oa0 = (floatx16)0.0f, oa1 = (floatx16)0.0f;
    float m_s = -1e37f, l_s = 0.0f;

    const int sr = tid >> 3;                       // 0..31
    const int su = (tid & 7) ^ (sr & 7);
    const char* ksrc = (const char*)(kg_ + ((long)b * Mq + sr) * Dq + h * 64 + su * 8);
    const char* vsrc = (const char*)(vtg + ((long)b * Dq + h * 64 + sr) * Mq + su * 8);
    const short* bbase = bmg + (qbase + q31) * Mq + hi * 4;

#define STAGE(bf, kt2) do {                                                   \
        const long j0b = (long)(kt2) * 64;                                    \
        char* kd = (char*)k_lds + (bf) * 8192 + w * 1024;                     \
        char* vd = (char*)v_lds + (bf) * 8192 + w * 1024;                     \
        gld16(ksrc + j0b * (Dq * 2), kd);                                     \
        gld16(ksrc + (j0b + 32) * (Dq * 2), kd + 4096);                       \
        gld16(vsrc + j0b * 2, vd);                                            \
        gld16(vsrc + 32L * Mq * 2 + j0b * 2, vd + 4096);                      \
    } while (0)

#define LOADBB(bb, kt2) do {                                                  \
        const short* brow_ = bbase + (long)(kt2) * 64;                        \
        _Pragma("unroll")                                                     \
        for (int kg = 0; kg < 2; ++kg)                                        \
            _Pragma("unroll")                                                 \
            for (int Qh = 0; Qh < 4; ++Qh)                                    \
                bb[kg * 4 + Qh] = *(const short4v*)(brow_ + kg * 32 + Qh * 8);\
    } while (0)

    short4v bbA[8], bbB[8];

    STAGE(0, 0);
    LOADBB(bbA, 0);
    __syncthreads();

    int buf = 0;
    for (int kt = 0; kt < 32; ++kt) {
        if (kt < 31) STAGE(buf ^ 1, kt + 1);
        LOADBB(bbB, (kt < 31) ? kt + 1 : 31);   // prefetch next tile's bias

        const char* kb = (const char*)k_lds + buf * 8192;
        const char* vb = (const char*)v_lds + buf * 8192;

        // C-init = bias (from bbA, loaded last interval), QK^T on top
        floatx16 sa0, sa1;
#pragma unroll
        for (int Qh = 0; Qh < 4; ++Qh)
#pragma unroll
            for (int e = 0; e < 4; ++e) {
                sa0[Qh * 4 + e] = bf2f(bbA[Qh][e]);
                sa1[Qh * 4 + e] = bf2f(bbA[4 + Qh][e]);
            }
        {
            short8 kf[4];
#pragma unroll
            for (int ks = 0; ks < 4; ++ks)
                kf[ks] = *(const short8*)(kb + q31 * 128 + (((2 * ks + hi) ^ (q31 & 7)) * 16));
#pragma unroll
            for (int ks = 0; ks < 4; ++ks)
                sa0 = __builtin_amdgcn_mfma_f32_32x32x16_bf16(kf[ks], qf[ks], sa0, 0, 0, 0);
        }
        {
            short8 kf[4];
            const int r1 = 32 + q31;
#pragma unroll
            for (int ks = 0; ks < 4; ++ks)
                kf[ks] = *(const short8*)(kb + r1 * 128 + (((2 * ks + hi) ^ (r1 & 7)) * 16));
#pragma unroll
            for (int ks = 0; ks < 4; ++ks)
                sa1 = __builtin_amdgcn_mfma_f32_32x32x16_bf16(kf[ks], qf[ks], sa1, 0, 0, 0);
        }

        // defer-max online softmax (R3/R5-proven; shfl_xor cross-half)
        {
            float a0 = fmaxf(fmaxf(sa0[0], sa0[1]), fmaxf(sa0[2], sa0[3]));
            float a1 = fmaxf(fmaxf(sa0[4], sa0[5]), fmaxf(sa0[6], sa0[7]));
            float a2 = fmaxf(fmaxf(sa0[8], sa0[9]), fmaxf(sa0[10], sa0[11]));
            float a3 = fmaxf(fmaxf(sa0[12], sa0[13]), fmaxf(sa0[14], sa0[15]));
            float a4 = fmaxf(fmaxf(sa1[0], sa1[1]), fmaxf(sa1[2], sa1[3]));
            float a5 = fmaxf(fmaxf(sa1[4], sa1[5]), fmaxf(sa1[6], sa1[7]));
            float a6 = fmaxf(fmaxf(sa1[8], sa1[9]), fmaxf(sa1[10], sa1[11]));
            float a7 = fmaxf(fmaxf(sa1[12], sa1[13]), fmaxf(sa1[14], sa1[15]));
            float pm = fmaxf(fmaxf(fmaxf(a0, a1), fmaxf(a2, a3)),
                             fmaxf(fmaxf(a4, a5), fmaxf(a6, a7)));
            pm = fmaxf(pm, __shfl_xor(pm, 32));
            if (!__all(pm <= m_s + 11.5f)) {
                const float mn = fmaxf(m_s, pm);
                const float al = exp2_fast(m_s - mn);
                l_s *= al;
                oa0 *= al; oa1 *= al;
                m_s = mn;
            }
        }
#pragma unroll
        for (int j = 0; j < 16; ++j) {
            sa0[j] = exp2_fast(sa0[j] - m_s);
            sa1[j] = exp2_fast(sa1[j] - m_s);
        }
        {
            const float t0 = (sa0[0] + sa0[1]) + (sa0[2] + sa0[3]);
            const float t1 = (sa0[4] + sa0[5]) + (sa0[6] + sa0[7]);
            const float t2 = (sa0[8] + sa0[9]) + (sa0[10] + sa0[11]);
            const float t3 = (sa0[12] + sa0[13]) + (sa0[14] + sa0[15]);
            const float t4 = (sa1[0] + sa1[1]) + (sa1[2] + sa1[3]);
            const float t5 = (sa1[4] + sa1[5]) + (sa1[6] + sa1[7]);
            const float t6 = (sa1[8] + sa1[9]) + (sa1[10] + sa1[11]);
            const float t7 = (sa1[12] + sa1[13]) + (sa1[14] + sa1[15]);
            float rs = ((t0 + t1) + (t2 + t3)) + ((t4 + t5) + (t6 + t7));
            rs += __shfl_xor(rs, 32);
            l_s += rs;
        }

        // pack P -> PV B-frags (cvt_pk + permlane32_swap)
        uint4v pw0, pw1, pw2, pw3;
        {
            unsigned w0 = cvtpk_bf16(sa0[0], sa0[1]);
            unsigned w1 = cvtpk_bf16(sa0[2], sa0[3]);
            unsigned w2 = cvtpk_bf16(sa0[4], sa0[5]);
            unsigned w3 = cvtpk_bf16(sa0[6], sa0[7]);
            swap32(w0, w2); swap32(w1, w3);
            pw0[0] = w0; pw0[1] = w1; pw0[2] = w2; pw0[3] = w3;
            unsigned w4 = cvtpk_bf16(sa0[8], sa0[9]);
            unsigned w5 = cvtpk_bf16(sa0[10], sa0[11]);
            unsigned w6 = cvtpk_bf16(sa0[12], sa0[13]);
            unsigned w7 = cvtpk_bf16(sa0[14], sa0[15]);
            swap32(w4, w6); swap32(w5, w7);
            pw1[0] = w4; pw1[1] = w5; pw1[2] = w6; pw1[3] = w7;
            unsigned x0 = cvtpk_bf16(sa1[0], sa1[1]);
            unsigned x1 = cvtpk_bf16(sa1[2], sa1[3]);
            unsigned x2 = cvtpk_bf16(sa1[4], sa1[5]);
            unsigned x3 = cvtpk_bf16(sa1[6], sa1[7]);
            swap32(x0, x2); swap32(x1, x3);
            pw2[0] = x0; pw2[1] = x1; pw2[2] = x2; pw2[3] = x3;
            unsigned x4 = cvtpk_bf16(sa1[8], sa1[9]);
            unsigned x5 = cvtpk_bf16(sa1[10], sa1[11]);
            unsigned x6 = cvtpk_bf16(sa1[12], sa1[13]);
            unsigned x7 = cvtpk_bf16(sa1[14], sa1[15]);
            swap32(x4, x6); swap32(x5, x7);
            pw3[0] = x4; pw3[1] = x5; pw3[2] = x6; pw3[3] = x7;
        }

        // PV (V frags scoped per dg)
        {
            short8 vf[4];
#pragma unroll
            for (int ks = 0; ks < 4; ++ks)
                vf[ks] = *(const short8*)(vb + q31 * 128 + (((2 * ks + hi) ^ (q31 & 7)) * 16));
            oa0 = __builtin_amdgcn_mfma_f32_32x32x16_bf16(vf[0], __builtin_bit_cast(short8, pw0), oa0, 0, 0, 0);
            oa0 = __builtin_amdgcn_mfma_f32_32x32x16_bf16(vf[1], __builtin_bit_cast(short8, pw1), oa0, 0, 0, 0);
            oa0 = __builtin_amdgcn_mfma_f32_32x32x16_bf16(vf[2], __builtin_bit_cast(short8, pw2), oa0, 0, 0, 0);
            oa0 = __builtin_amdgcn_mfma_f32_32x32x16_bf16(vf[3], __builtin_bit_cast(short8, pw3), oa0, 0, 0, 0);
        }
        {
            short8 vf[4];
            const int r1 = 32 + q31;
#pragma unroll
            for (int ks = 0; ks < 4; ++ks)
                vf[ks] = *(const short8*)(vb + r1 * 128 + (((2 * ks + hi) ^ (r1 & 7)) * 16));
            oa1 = __builtin_amdgcn_mfma_f32_32x32x16_bf16(vf[0], __builtin_bit_cast(short8, pw0), oa1, 0, 0, 0);
            oa1 = __builtin_amdgcn_mfma_f32_32x32x16_bf16(vf[1], __builtin_bit_cast(short8, pw1), oa1, 0, 0, 0);
            oa1 = __builtin_amdgcn_mfma_f32_32x32x16_bf16(vf[2], __builtin_bit_cast(short8, pw2), oa1, 0, 0, 0);
            oa1 = __builtin_amdgcn_mfma_f32_32x32x16_bf16(vf[3], __builtin_bit_cast(short8, pw3), oa1, 0, 0, 0);
        }

        // rotate bias prefetch regs (static indices)
#pragma unroll
        for (int i = 0; i < 8; ++i) bbA[i] = bbB[i];

        __syncthreads();
        buf ^= 1;
    }
#undef STAGE
#undef LOADBB

    const float invl = 1.0f / l_s;
    short* op = outg + (qbase + q31) * Dq + h * 64;
#pragma unroll
    for (int Qh = 0; Qh < 4; ++Qh) {
        short4v t0v, t1v;
#pragma unroll
        for (int e = 0; e < 4; ++e) {
            t0v[e] = f2bf(oa0[Qh * 4 + e] * invl);
            t1v[e] = f2bf(oa1[Qh * 4 + e] * invl);
        }
        *(short4v*)(op + Qh * 8 + hi * 4) = t0v;
        *(short4v*)(op + 32 + Qh * 8 + hi * 4) = t1v;
    }
}

// ---------------------------------------------------------------------------
extern "C" void kernel_launch(void* const* d_in, const int* in_sizes, int n_in,
                              void* d_out, int out_size, void* d_ws, size_t ws_size,
                              hipStream_t stream)
{
    const float* Q    = (const float*)d_in[0];
    const float* K    = (const float*)d_in[1];
    const float* V    = (const float*)d_in[2];
    const float* bias = (const float*)d_in[3];
    const int*   mask = (const int*)d_in[4];
    const float* Wq   = (const float*)d_in[5];
    const float* bq   = (const float*)d_in[6];
    const float* Wk   = (const float*)d_in[7];
    const float* bk   = (const float*)d_in[8];
    const float* Wv   = (const float*)d_in[9];
    const float* bv   = (const float*)d_in[10];
    const float* Wo   = (const float*)d_in[11];
    const float* bo   = (const float*)d_in[12];

    // ws layout (shorts), 109 MB total (R3/R5-proven footprint):
    //   q | k | vT | a(=qin first) | bm(=kin/vin first, 2TSZ) | W (4x1.05M)
    const size_t TSZ = (size_t)Bq * Nq * Dq;       // 8,388,608
    short* q_ws  = (short*)d_ws;
    short* k_ws  = q_ws  + TSZ;
    short* vt_ws = k_ws  + TSZ;
    short* a_ws  = vt_ws + TSZ;
    short* bm_ws = a_ws  + TSZ;
    short* w_ws  = bm_ws + 2 * TSZ;
    short* qin_ws = a_ws;
    short* kin_ws = bm_ws;
    short* vin_ws = bm_ws + TSZ;
    (void)ws_size;

    cvt_bf<<<dim3(512, 4), dim3(256), 0, stream>>>(Wq, Wk, Wv, Wo, w_ws, (long)Dq * Dq);
    cvt_bf<<<dim3(4096, 3), dim3(256), 0, stream>>>(Q, K, V, V, qin_ws, (long)TSZ);

    GB g1{};
    g1.A[0] = qin_ws; g1.A[1] = kin_ws; g1.A[2] = vin_ws;
    g1.W[0] = w_ws; g1.W[1] = w_ws + Dq * Dq; g1.W[2] = w_ws + 2 * Dq * Dq;
    g1.bias[0] = bq; g1.bias[1] = bk; g1.bias[2] = bv;
    g1.C[0] = q_ws; g1.C[1] = k_ws; g1.C[2] = vt_ws;
    g1.scale[0] = 0.125f * 1.44269504f; g1.scale[1] = 1.0f; g1.scale[2] = 1.0f;
    g1.omode[0] = 0; g1.omode[1] = 0; g1.omode[2] = 1;
    gemm_all<<<dim3(64, 8, 3), dim3(256), 0, stream>>>(g1, Dq);

    bias_prep<<<dim3(8192), dim3(256), 0, stream>>>(bias, mask, bm_ws);

    attn_fused<<<dim3(1024), dim3(256), 0, stream>>>(q_ws, k_ws, vt_ws, bm_ws, a_ws);

    GB g2{};
    g2.A[0] = a_ws;
    g2.W[0] = w_ws + 3 * Dq * Dq;
    g2.bias[0] = bo;
    g2.C[0] = d_out;
    g2.scale[0] = 1.0f;
    g2.omode[0] = 2;
    gemm_all<<<dim3(64, 8, 1), dim3(256), 0, stream>>>(g2, Dq);
}